// Round 12
// baseline (251.434 us; speedup 1.0000x reference)
//
#include <hip/hip_runtime.h>

// ---- problem constants ----
#define NTOK 8192      // B*N = 8*1024
#define CDIM 768
#define HIDD 3072
#define NQKV 2304
#define SEQL 1024
#define NHEAD 12

typedef int i32x4 __attribute__((ext_vector_type(4)));
typedef float f32x4 __attribute__((ext_vector_type(4)));
typedef signed char sc16 __attribute__((ext_vector_type(16)));
typedef unsigned short us4 __attribute__((ext_vector_type(4)));

__device__ __forceinline__ unsigned short f32_to_bf16(float f) {
    unsigned int u = __float_as_uint(f);
    u += 0x7FFFu + ((u >> 16) & 1u);
    return (unsigned short)(u >> 16);
}
__device__ __forceinline__ float bf16_to_f32(unsigned short h) {
    return __uint_as_float(((unsigned)h) << 16);
}

// async global->LDS, 16B per lane. Dest must be wave-uniform base + lane*16.
__device__ __forceinline__ void gload_lds16(const void* g, void* l) {
    __builtin_amdgcn_global_load_lds(
        (const __attribute__((address_space(1))) unsigned int*)g,
        (__attribute__((address_space(3))) unsigned int*)l, 16, 0, 0);
}

// sign(w) as i8 +-1 (x>=0 -> +1 per ste_sign)
__global__ void sign_w_kernel(const float* __restrict__ w, signed char* __restrict__ ws, int n) {
    int i = blockIdx.x * blockDim.x + threadIdx.x;
    int stride = gridDim.x * blockDim.x;
    for (; i < n; i += stride)
        ws[i] = (w[i] >= 0.0f) ? 1 : -1;
}

// fused: sign(w) i8 + alpha[row] = mean|w[row,:]|
// PERM: k-index within each 64-group permuted by pi(j) = (j&15)*4 + (j>>4)
template<bool PERM>
__global__ void __launch_bounds__(256) signalpha_kernel(const float* __restrict__ w,
                                                        signed char* __restrict__ ws,
                                                        float* __restrict__ alpha, int K) {
    int row = blockIdx.x;
    const float* wr = w + (size_t)row * K;
    signed char* wsr = ws + (size_t)row * K;
    float s = 0.f;
    for (int i = threadIdx.x; i < K; i += 256) {
        float v = wr[i];
        int ip = PERM ? ((i & ~63) | (((i & 15) << 2) | ((i >> 4) & 3))) : i;
        wsr[ip] = (v >= 0.f) ? 1 : -1;
        s += fabsf(v);
    }
    for (int off = 32; off > 0; off >>= 1) s += __shfl_down(s, off);
    __shared__ float red[4];
    if ((threadIdx.x & 63) == 0) red[threadIdx.x >> 6] = s;
    __syncthreads();
    if (threadIdx.x == 0) alpha[row] = (red[0] + red[1] + red[2] + red[3]) / (float)K;
}

// LayerNorm over 768 -> sign as i8 +-1 (LN1 path)
__global__ void __launch_bounds__(256) ln_sign_kernel(const float* __restrict__ x, const float* __restrict__ g,
                                                      const float* __restrict__ b, signed char* __restrict__ out) {
    int row = blockIdx.x;
    const float* xr = x + (size_t)row * CDIM;
    float v0 = xr[threadIdx.x], v1 = xr[threadIdx.x + 256], v2 = xr[threadIdx.x + 512];
    float s = v0 + v1 + v2, s2 = v0 * v0 + v1 * v1 + v2 * v2;
    for (int off = 32; off > 0; off >>= 1) { s += __shfl_down(s, off); s2 += __shfl_down(s2, off); }
    __shared__ float red[8];
    if ((threadIdx.x & 63) == 0) { red[threadIdx.x >> 6] = s; red[4 + (threadIdx.x >> 6)] = s2; }
    __syncthreads();
    float ts = red[0] + red[1] + red[2] + red[3];
    float t2 = red[4] + red[5] + red[6] + red[7];
    float mu = ts * (1.0f / CDIM);
    float var = t2 * (1.0f / CDIM) - mu * mu;
    float rstd = rsqrtf(var + 1e-5f);
    signed char* orow = out + (size_t)row * CDIM;
    float vv[3] = {v0, v1, v2};
#pragma unroll
    for (int p = 0; p < 3; p++) {
        int i = threadIdx.x + p * 256;
        float val = (vv[p] - mu) * rstd * g[i] + b[i];
        orow[i] = (val >= 0.f) ? 1 : -1;
    }
}

// LayerNorm over 768 (bf16 x1 input) -> per-row i8 quant; rowscale[row] = rowmax/127
__global__ void __launch_bounds__(256) ln2q_kernel(const unsigned short* __restrict__ x, const float* __restrict__ g,
                                                   const float* __restrict__ b, signed char* __restrict__ out,
                                                   float* __restrict__ rowscale) {
    int row = blockIdx.x;
    const unsigned short* xr = x + (size_t)row * CDIM;
    float v0 = bf16_to_f32(xr[threadIdx.x]);
    float v1 = bf16_to_f32(xr[threadIdx.x + 256]);
    float v2 = bf16_to_f32(xr[threadIdx.x + 512]);
    float s = v0 + v1 + v2, s2 = v0 * v0 + v1 * v1 + v2 * v2;
    for (int off = 32; off > 0; off >>= 1) { s += __shfl_down(s, off); s2 += __shfl_down(s2, off); }
    __shared__ float red[8];
    __shared__ float redm[4];
    if ((threadIdx.x & 63) == 0) { red[threadIdx.x >> 6] = s; red[4 + (threadIdx.x >> 6)] = s2; }
    __syncthreads();
    float ts = red[0] + red[1] + red[2] + red[3];
    float t2 = red[4] + red[5] + red[6] + red[7];
    float mu = ts * (1.0f / CDIM);
    float var = t2 * (1.0f / CDIM) - mu * mu;
    float rstd = rsqrtf(var + 1e-5f);
    float a0 = (v0 - mu) * rstd * g[threadIdx.x] + b[threadIdx.x];
    float a1 = (v1 - mu) * rstd * g[threadIdx.x + 256] + b[threadIdx.x + 256];
    float a2v = (v2 - mu) * rstd * g[threadIdx.x + 512] + b[threadIdx.x + 512];
    float mx = fmaxf(fabsf(a0), fmaxf(fabsf(a1), fabsf(a2v)));
    for (int off = 32; off > 0; off >>= 1) mx = fmaxf(mx, __shfl_down(mx, off));
    if ((threadIdx.x & 63) == 0) redm[threadIdx.x >> 6] = mx;
    __syncthreads();
    float rmax = fmaxf(fmaxf(redm[0], redm[1]), fmaxf(redm[2], redm[3]));
    rmax = fmaxf(rmax, 1e-20f);
    float inv = 127.f / rmax;
    signed char* orow = out + (size_t)row * CDIM;
    orow[threadIdx.x]       = (signed char)__float2int_rn(a0 * inv);
    orow[threadIdx.x + 256] = (signed char)__float2int_rn(a1 * inv);
    orow[threadIdx.x + 512] = (signed char)__float2int_rn(a2v * inv);
    if (threadIdx.x == 0) rowscale[row] = rmax * (1.f / 127.f);
}

// ============================================================================
// 8-phase i8 GEMM: 256x128 tile, 8 waves (2m x 4n), BK=128 bytes (2 k-halves),
// 4 phases per K-tile: {8/6 ds_read || stage 1 half-tile || barrier || MFMA
// under setprio || counted vmcnt at odd phases || barrier}.
// Per-wave stage stream per K-tile: [A-k0(2), B-k0(1), A-k1(2), B-k1(1)].
// vmcnt(3) at phase1-end forces current tile's k1; at phase3-end forces next
// tile's k0; loads always span >=2 phases (never drained mid-loop).
// ============================================================================
enum { EPI_QKV = 0, EPI_GELU = 1, EPI_PROJ = 2, EPI_FC2 = 3 };
#define MSCALE_INV 16.0f

template<int EPI>
__global__ void __launch_bounds__(512, 2) gemm8p(
    const signed char* __restrict__ A, const signed char* __restrict__ B,
    int N, int K,
    const float* __restrict__ alpha, const float* __restrict__ bias,
    const float* __restrict__ ls,
    const float* __restrict__ residF, const unsigned short* __restrict__ residH,
    const float* __restrict__ rowscale, float ascale,
    float* __restrict__ outF, unsigned short* __restrict__ outH,
    signed char* __restrict__ outB, signed char* __restrict__ vtB)
{
    __shared__ __align__(16) char lds_raw[98304];
    auto Ab = (signed char (*)[2][256][64])lds_raw;             // [dbuf][ksub][row][byte]
    auto Bb = (signed char (*)[2][128][64])(lds_raw + 65536);

    const int tid = threadIdx.x, ln = tid & 63, w = tid >> 6;
    const int wm = w >> 2, wn = w & 3;        // 2 M-waves x 4 N-waves
    const int lq = ln & 15, khi = ln >> 4;

    const int nwg = gridDim.x * gridDim.y;
    const int id = blockIdx.y * gridDim.x + blockIdx.x;
    const int nid = (id & 7) * (nwg >> 3) + (id >> 3);
    const int bxs = nid % gridDim.x, bys = nid / gridDim.x;
    const int bm = bys * 256, bn = bxs * 128;

    // ---- T14 preloads (RESID only): oldest in vmcnt order, forced at prologue ----
    const int ec4 = (tid & 31) * 4, er = tid >> 5;
    f32x4 a4, b4, l4;
    f32x4 rF[16];
    us4 rH[16];
    if constexpr (EPI >= EPI_PROJ) {
        a4 = *(const f32x4*)&alpha[bn + ec4];
        b4 = *(const f32x4*)&bias[bn + ec4];
        l4 = *(const f32x4*)&ls[bn + ec4];
#pragma unroll
        for (int h = 0; h < 2; h++)
#pragma unroll
            for (int q = 0; q < 8; q++) {
                size_t g = (size_t)(bm + h * 128 + q * 16 + er) * N + bn + ec4;
                if constexpr (EPI == EPI_FC2) rH[h * 8 + q] = *(const us4*)&residH[g];
                else                          rF[h * 8 + q] = *(const f32x4*)&residF[g];
            }
    }

    const i32x4 iz = {0, 0, 0, 0};
    i32x4 acc[8][2];
#pragma unroll
    for (int m = 0; m < 8; m++)
#pragma unroll
        for (int n = 0; n < 2; n++) acc[m][n] = iz;

    const int gsw = ((tid & 3) ^ ((tid >> 3) & 3)) * 16;   // pre-swizzled source slot
    const int sa = 16 * (khi ^ ((lq >> 1) & 3));           // swizzled LDS read slot
    const int sr4 = tid >> 2, sc = (tid & 3) * 16;

    auto STAGE_A = [&](int d, int kt, int ks) {
#pragma unroll
        for (int j = 0; j < 2; j++) {
            int row = j * 128 + sr4;
            gload_lds16(A + (size_t)(bm + row) * K + kt * 128 + ks * 64 + gsw,
                        &Ab[d][ks][row][sc]);
        }
    };
    auto STAGE_B = [&](int d, int kt, int ks) {
        int row = sr4 & 127;   // 0..127 (512 threads: rows repeated? no: sr4 0..127)
        gload_lds16(B + (size_t)(bn + row) * K + kt * 128 + ks * 64 + gsw,
                    &Bb[d][ks][row][sc]);
    };

    const int nst = K >> 7;   // K-tiles of 128 bytes
    // prologue: stage tile 0 (order: A-k0, B-k0, A-k1, B-k1)
    STAGE_A(0, 0, 0); STAGE_B(0, 0, 0); STAGE_A(0, 0, 1); STAGE_B(0, 0, 1);
    asm volatile("s_waitcnt vmcnt(3)" ::: "memory");   // k0 (+preloads) landed; k1 flying
    __builtin_amdgcn_s_barrier();

    int cur = 0;
#pragma unroll 1
    for (int t = 0; t < nst; t++) {
        const bool hn = (t + 1 < nst);
#pragma unroll
        for (int p = 0; p < 4; p++) {
            const int ks = p >> 1, mq = p & 1;
            i32x4 aF[4], bF[2];
#pragma unroll
            for (int mf = 0; mf < 4; mf++)
                aF[mf] = *(const i32x4*)&Ab[cur][ks][wm * 128 + mq * 64 + mf * 16 + lq][sa];
#pragma unroll
            for (int nf = 0; nf < 2; nf++)
                bF[nf] = *(const i32x4*)&Bb[cur][ks][wn * 32 + nf * 16 + lq][sa];
            if (hn) {
                if (p == 0)      STAGE_A(cur ^ 1, t + 1, 0);
                else if (p == 1) STAGE_B(cur ^ 1, t + 1, 0);
                else if (p == 2) STAGE_A(cur ^ 1, t + 1, 1);
                else             STAGE_B(cur ^ 1, t + 1, 1);
            }
            __builtin_amdgcn_s_barrier();
            __builtin_amdgcn_s_setprio(1);
#pragma unroll
            for (int mf = 0; mf < 4; mf++)
#pragma unroll
                for (int nf = 0; nf < 2; nf++)
                    acc[mq * 4 + mf][nf] =
                        __builtin_amdgcn_mfma_i32_16x16x64_i8(aF[mf], bF[nf], acc[mq * 4 + mf][nf], 0, 0, 0);
            __builtin_amdgcn_s_setprio(0);
            if (p == 1 || p == 3) {
                if (hn) asm volatile("s_waitcnt vmcnt(3)" ::: "memory");
                else    asm volatile("s_waitcnt vmcnt(0)" ::: "memory");
            }
            __builtin_amdgcn_s_barrier();
        }
        cur ^= 1;
    }

    const int r0 = bm + wm * 128;

    if constexpr (EPI == EPI_QKV) {
        if (bn < 1536) {
            // Q,K: pi-packed (u16 pair: this wave owns bytes (wn&1)*2 + {0,1})
#pragma unroll
            for (int m = 0; m < 8; m++)
#pragma unroll
                for (int i = 0; i < 4; i++) {
                    int r = r0 + m * 16 + khi * 4 + i;
                    unsigned short pk =
                        (unsigned short)(unsigned char)(signed char)((acc[m][0][i] >= 0) ? 1 : -1) |
                        ((unsigned short)(unsigned char)(signed char)((acc[m][1][i] >= 0) ? 1 : -1) << 8);
                    *(unsigned short*)(outB + (size_t)r * 1536 + bn + (wn >> 1) * 64 + lq * 4 + (wn & 1) * 2) = pk;
                }
        } else {
            // V -> vt[(batch*12+hh)*64+dd][token], token-packed u32 (true d)
#pragma unroll
            for (int m = 0; m < 8; m++)
#pragma unroll
                for (int n = 0; n < 2; n++) {
                    int cg = bn + wn * 32 + n * 16 + lq - 1536;
                    int hh = cg >> 6, dd = cg & 63;
                    int rb = r0 + m * 16 + khi * 4;
                    unsigned pk = 0;
#pragma unroll
                    for (int i = 0; i < 4; i++)
                        pk |= (unsigned)(unsigned char)(signed char)((acc[m][n][i] >= 0) ? 1 : -1) << (8 * i);
                    *(unsigned*)(vtB + (((size_t)(rb >> 10) * NHEAD + hh) * 64 + dd) * SEQL + (rb & 1023)) = pk;
                }
        }
    } else if constexpr (EPI == EPI_GELU) {
        float al[2], bi[2];
#pragma unroll
        for (int n = 0; n < 2; n++) {
            int c = bn + wn * 32 + n * 16 + lq;
            al[n] = alpha[c]; bi[n] = bias[c];
        }
#pragma unroll
        for (int m = 0; m < 8; m++)
#pragma unroll
            for (int i = 0; i < 4; i++) {
                int r = r0 + m * 16 + khi * 4 + i;
                float rs = rowscale[r];
                unsigned short pk = 0;
#pragma unroll
                for (int n = 0; n < 2; n++) {
                    float t = al[n] * ((float)acc[m][n][i] * rs) + bi[n];
                    float y2 = 1.5957691f * t + 0.07135481f * t * t * t;
                    float ge = t * __builtin_amdgcn_rcpf(1.0f + __expf(-y2));
                    float qf = fminf(fmaxf(ge * MSCALE_INV, -127.f), 127.f);
                    pk |= (unsigned short)(unsigned char)(signed char)__float2int_rn(qf) << (8 * n);
                }
                *(unsigned short*)(outB + (size_t)r * N + bn + (wn >> 1) * 64 + lq * 4 + (wn & 1) * 2) = pk;
            }
    } else {
        // RESID: 2-pass LDS transpose (Cf 128x132 f32 aliases staging LDS), then
        // pure FMA + coalesced stores using preloaded resid/alpha/bias/ls.
        float (*Cf)[132] = (float (*)[132])lds_raw;
#pragma unroll 1
        for (int h = 0; h < 2; h++) {
            __syncthreads();
            if (wm == h) {
#pragma unroll
                for (int m = 0; m < 8; m++)
#pragma unroll
                    for (int n = 0; n < 2; n++)
#pragma unroll
                        for (int i = 0; i < 4; i++)
                            Cf[m * 16 + khi * 4 + i][wn * 32 + n * 16 + lq] =
                                (float)acc[m][n][i] * ascale;
            }
            __syncthreads();
#pragma unroll
            for (int q = 0; q < 8; q++) {
                int row = q * 16 + er;
                f32x4 v4 = *(const f32x4*)&Cf[row][ec4];
                size_t g = (size_t)(bm + h * 128 + row) * N + bn + ec4;
                if constexpr (EPI == EPI_FC2) {
                    us4 rh = rH[h * 8 + q];
                    f32x4 r;
                    r.x = bf16_to_f32(rh.x); r.y = bf16_to_f32(rh.y);
                    r.z = bf16_to_f32(rh.z); r.w = bf16_to_f32(rh.w);
                    f32x4 o4 = r + l4 * (a4 * v4 + b4);
                    *(f32x4*)&outF[g] = o4;
                } else {
                    f32x4 o4 = rF[h * 8 + q] + l4 * (a4 * v4 + b4);
                    us4 hh;
                    hh.x = f32_to_bf16(o4.x); hh.y = f32_to_bf16(o4.y);
                    hh.z = f32_to_bf16(o4.z); hh.w = f32_to_bf16(o4.w);
                    *(us4*)&outH[g] = hh;
                }
            }
        }
    }
}

// ---------- binary attention v2 (exact i8) ----------
__global__ void __launch_bounds__(256) attn_v2(const signed char* __restrict__ qk,
                                               const signed char* __restrict__ vt,
                                               signed char* __restrict__ a2) {
    const int id = blockIdx.x;                       // 0..767
    const int nid = (id & 7) * 96 + (id >> 3);
    const int bh = nid >> 3, qb = nid & 7;
    const int b = bh / NHEAD, h = bh % NHEAD;
    const int tid = threadIdx.x, ln = tid & 63, w = tid >> 6;
    const int lq = ln & 15, khi = ln >> 4;

    __shared__ signed char Ks[64][80];
    __shared__ signed char Vts[64][80];
    __shared__ signed char Pw[4][32][80];

    const size_t tokbase = (size_t)b * SEQL;
    const int q0 = qb * 128 + w * 32;
    const int str = tid >> 2, stc = (tid & 3) * 16;
    const size_t vtrow = ((size_t)bh * 64 + str) * SEQL;

    i32x4 qfrag[2];
#pragma unroll
    for (int qf = 0; qf < 2; qf++)
        qfrag[qf] = *(const i32x4*)(qk + (tokbase + q0 + qf * 16 + lq) * 1536 + h * 64 + khi * 16);

    const i32x4 iz = {0, 0, 0, 0};
    i32x4 o[2][4];
#pragma unroll
    for (int qf = 0; qf < 2; qf++)
#pragma unroll
        for (int df = 0; df < 4; df++) o[qf][df] = iz;

    auto LOADJ = [&](int j, sc16& kr, sc16& vr) {
        kr = *(const sc16*)(qk + (tokbase + j * 64 + str) * 1536 + 768 + h * 64 + stc);
        vr = *(const sc16*)(vt + vtrow + j * 64 + stc);
    };
    auto STORE = [&](const sc16& kr, const sc16& vr) {
        *(sc16*)&Ks[str][stc] = kr;
        *(sc16*)&Vts[str][stc] = vr;
    };
    auto COMPUTE = [&]() {
        i32x4 kfrag[4];
#pragma unroll
        for (int kf = 0; kf < 4; kf++)
            kfrag[kf] = *(const i32x4*)&Ks[kf * 16 + lq][khi * 16];
#pragma unroll
        for (int kf = 0; kf < 4; kf++) {
#pragma unroll
            for (int qf = 0; qf < 2; qf++) {
                i32x4 st = __builtin_amdgcn_mfma_i32_16x16x64_i8(kfrag[kf], qfrag[qf], iz, 0, 0, 0);
                unsigned pb = (st[0] > 0 ? 1u : 0u) | (st[1] > 0 ? 0x100u : 0u) |
                              (st[2] > 0 ? 0x10000u : 0u) | (st[3] > 0 ? 0x1000000u : 0u);
                *(unsigned*)&Pw[w][qf * 16 + lq][kf * 16 + khi * 4] = pb;
            }
        }
        i32x4 pa[2];
#pragma unroll
        for (int qf = 0; qf < 2; qf++)
            pa[qf] = *(const i32x4*)&Pw[w][qf * 16 + lq][khi * 16];
#pragma unroll
        for (int df = 0; df < 4; df++) {
            i32x4 vfr = *(const i32x4*)&Vts[df * 16 + lq][khi * 16];
#pragma unroll
            for (int qf = 0; qf < 2; qf++)
                o[qf][df] = __builtin_amdgcn_mfma_i32_16x16x64_i8(pa[qf], vfr, o[qf][df], 0, 0, 0);
        }
    };

    sc16 ka, va, kb, vb;
    LOADJ(0, ka, va);
#pragma unroll 1
    for (int jj = 0; jj < 16; jj += 2) {
        __syncthreads();
        STORE(ka, va);
        __syncthreads();
        LOADJ(jj + 1, kb, vb);
        COMPUTE();
        __syncthreads();
        STORE(kb, vb);
        __syncthreads();
        if (jj + 2 < 16) LOADJ(jj + 2, ka, va);
        COMPUTE();
    }

    // epilogue: pi-packed u32: a2[token][h*64 + lq*4 + df] = sign(O[.][df*16+lq])
#pragma unroll
    for (int qf = 0; qf < 2; qf++)
#pragma unroll
        for (int i = 0; i < 4; i++) {
            int qrow = q0 + qf * 16 + khi * 4 + i;
            unsigned pk = 0;
#pragma unroll
            for (int df = 0; df < 4; df++)
                pk |= (unsigned)(unsigned char)(signed char)((o[qf][df][i] >= 0) ? 1 : -1) << (8 * df);
            *(unsigned*)(a2 + (tokbase + qrow) * CDIM + h * 64 + lq * 4) = pk;
        }
}

// ---------- workspace layout (bytes) ----------
static const size_t OFF_WQKV  = 0;          // 2304*768   = 1769472
static const size_t OFF_WPROJ = 1769472;    // 768*768    = 589824
static const size_t OFF_WFC1  = 2359296;    // 3072*768   = 2359296
static const size_t OFF_WFC2  = 4718592;    // 768*3072   = 2359296
static const size_t OFF_APROJ = 7077888;    // 768*4
static const size_t OFF_AFC1  = 7080960;    // 3072*4
static const size_t OFF_AFC2  = 7093248;    // 768*4
static const size_t OFF_H2SC  = 7096320;    // 8192*4
static const size_t OFF_QK    = 7129088;    // 8192*1536  = 12582912 (dead after attn)
static const size_t OFF_VT    = 19712000;   // 96*64*1024 = 6291456  (dead after attn)
static const size_t OFF_A1    = 26003456;   // 8192*768   = 6291456
static const size_t OFF_A2    = 32294912;   // 8192*768   = 6291456
static const size_t OFF_M1    = 38586368;   // 8192*3072  = 25165824
static const size_t OFF_H2    = 63752192;   // 8192*768   = 6291456
// x1b (bf16, 12582912 B) aliases OFF_QK: qk dead when proj runs.
static const size_t OFF_X1B   = OFF_QK;
// total = 70043648 bytes

extern "C" void kernel_launch(void* const* d_in, const int* in_sizes, int n_in,
                              void* d_out, int out_size, void* d_ws, size_t ws_size,
                              hipStream_t stream) {
    const float* x      = (const float*)d_in[0];
    const float* ln1_g  = (const float*)d_in[1];
    const float* ln1_b  = (const float*)d_in[2];
    const float* w_qkv  = (const float*)d_in[3];
    const float* w_proj = (const float*)d_in[4];
    const float* b_proj = (const float*)d_in[5];
    const float* ls1_g  = (const float*)d_in[6];
    const float* ln2_g  = (const float*)d_in[7];
    const float* ln2_b  = (const float*)d_in[8];
    const float* w_fc1  = (const float*)d_in[9];
    const float* b_fc1  = (const float*)d_in[10];
    const float* w_fc2  = (const float*)d_in[11];
    const float* b_fc2  = (const float*)d_in[12];
    const float* ls2_g  = (const float*)d_in[13];
    float* out = (float*)d_out;

    char* ws = (char*)d_ws;
    signed char* wqkv_s  = (signed char*)(ws + OFF_WQKV);
    signed char* wproj_s = (signed char*)(ws + OFF_WPROJ);
    signed char* wfc1_s  = (signed char*)(ws + OFF_WFC1);
    signed char* wfc2_s  = (signed char*)(ws + OFF_WFC2);
    float* a_proj  = (float*)(ws + OFF_APROJ);
    float* a_fc1   = (float*)(ws + OFF_AFC1);
    float* a_fc2   = (float*)(ws + OFF_AFC2);
    float* h2scale = (float*)(ws + OFF_H2SC);
    signed char* qk   = (signed char*)(ws + OFF_QK);
    signed char* vt   = (signed char*)(ws + OFF_VT);
    signed char* a1   = (signed char*)(ws + OFF_A1);
    signed char* a2   = (signed char*)(ws + OFF_A2);
    signed char* m1   = (signed char*)(ws + OFF_M1);
    signed char* h2   = (signed char*)(ws + OFF_H2);
    unsigned short* x1b = (unsigned short*)(ws + OFF_X1B);

    // weight prep (wproj/wfc2 k-dims pi-permuted to match a2/m1 producers)
    sign_w_kernel<<<512, 256, 0, stream>>>(w_qkv, wqkv_s, NQKV * CDIM);
    signalpha_kernel<true><<<CDIM, 256, 0, stream>>>(w_proj, wproj_s, a_proj, CDIM);
    signalpha_kernel<false><<<HIDD, 256, 0, stream>>>(w_fc1,  wfc1_s,  a_fc1,  CDIM);
    signalpha_kernel<true><<<CDIM, 256, 0, stream>>>(w_fc2,  wfc2_s,  a_fc2,  HIDD);

    // LN1 + sign
    ln_sign_kernel<<<NTOK, 256, 0, stream>>>(x, ln1_g, ln1_b, a1);

    // QKV: sign(a1 @ wqkv^T); Q,K -> qk (pi-packed), V -> vt transposed
    gemm8p<EPI_QKV><<<dim3(NQKV / 128, NTOK / 256), 512, 0, stream>>>(
        a1, wqkv_s, NQKV, CDIM, nullptr, nullptr, nullptr, nullptr, nullptr,
        nullptr, 1.0f, nullptr, nullptr, qk, vt);

    // binary attention -> sign(O) (exact i8)
    attn_v2<<<768, 256, 0, stream>>>(qk, vt, a2);

    // proj + layerscale residual: x1(bf16) = x + ls1*(ap*acc + bp)
    gemm8p<EPI_PROJ><<<dim3(CDIM / 128, NTOK / 256), 512, 0, stream>>>(
        a2, wproj_s, CDIM, CDIM, a_proj, b_proj, ls1_g, x, nullptr,
        nullptr, 1.0f, nullptr, x1b, nullptr, nullptr);

    // LN2 (bf16 x1) + per-row i8 quant
    ln2q_kernel<<<NTOK, 256, 0, stream>>>(x1b, ln2_g, ln2_b, h2, h2scale);

    // fc1 + gelu -> fixed-scale i8 (pi-packed hidden layout)
    gemm8p<EPI_GELU><<<dim3(HIDD / 128, NTOK / 256), 512, 0, stream>>>(
        h2, wfc1_s, HIDD, CDIM, a_fc1, b_fc1, nullptr, nullptr, nullptr,
        h2scale, 1.0f, nullptr, nullptr, m1, nullptr);

    // fc2 + final residual: out(f32) = x1 + ls2*(af2*acc/16 + bf2)
    gemm8p<EPI_FC2><<<dim3(CDIM / 128, NTOK / 256), 512, 0, stream>>>(
        m1, wfc2_s, CDIM, HIDD, a_fc2, b_fc2, ls2_g, nullptr, x1b,
        nullptr, 1.0f / MSCALE_INV, out, nullptr, nullptr, nullptr);
}

// Round 13
// 157.549 us; speedup vs baseline: 1.5959x; 1.5959x over previous
//
#include <hip/hip_runtime.h>

// ---- problem constants ----
#define NTOK 8192      // B*N = 8*1024
#define CDIM 768
#define HIDD 3072
#define NQKV 2304
#define SEQL 1024
#define NHEAD 12

typedef int i32x4 __attribute__((ext_vector_type(4)));
typedef float f32x4 __attribute__((ext_vector_type(4)));
typedef signed char sc16 __attribute__((ext_vector_type(16)));
typedef unsigned short us4 __attribute__((ext_vector_type(4)));

__device__ __forceinline__ unsigned short f32_to_bf16(float f) {
    unsigned int u = __float_as_uint(f);
    u += 0x7FFFu + ((u >> 16) & 1u);
    return (unsigned short)(u >> 16);
}
__device__ __forceinline__ float bf16_to_f32(unsigned short h) {
    return __uint_as_float(((unsigned)h) << 16);
}

// async global->LDS, 16B per lane. Dest must be wave-uniform base + lane*16.
__device__ __forceinline__ void gload_lds16(const void* g, void* l) {
    __builtin_amdgcn_global_load_lds(
        (const __attribute__((address_space(1))) unsigned int*)g,
        (__attribute__((address_space(3))) unsigned int*)l, 16, 0, 0);
}

// ============================================================================
// Fused front-end: all weight prep (sign + alpha, optional pi-perm) AND
// LN1+sign. All rows are independent -> one dispatch instead of five.
// Block ranges: [0,768) wproj | [768,3840) wfc1 | [3840,4608) wfc2 |
//               [4608,6912) wqkv (sign only) | [6912,15104) LN1 rows.
// ============================================================================
__global__ void __launch_bounds__(256) prep_all(
    const float* __restrict__ w_proj, const float* __restrict__ w_fc1,
    const float* __restrict__ w_fc2,  const float* __restrict__ w_qkv,
    signed char* __restrict__ wproj_s, signed char* __restrict__ wfc1_s,
    signed char* __restrict__ wfc2_s,  signed char* __restrict__ wqkv_s,
    float* __restrict__ a_proj, float* __restrict__ a_fc1, float* __restrict__ a_fc2,
    const float* __restrict__ x, const float* __restrict__ ln1_g,
    const float* __restrict__ ln1_b, signed char* __restrict__ a1)
{
    const int blk = blockIdx.x;
    __shared__ float red[8];

    if (blk >= 6912) {
        // ---- LN1 + sign ----
        int row = blk - 6912;
        const float* xr = x + (size_t)row * CDIM;
        float v0 = xr[threadIdx.x], v1 = xr[threadIdx.x + 256], v2 = xr[threadIdx.x + 512];
        float s = v0 + v1 + v2, s2 = v0 * v0 + v1 * v1 + v2 * v2;
        for (int off = 32; off > 0; off >>= 1) { s += __shfl_down(s, off); s2 += __shfl_down(s2, off); }
        if ((threadIdx.x & 63) == 0) { red[threadIdx.x >> 6] = s; red[4 + (threadIdx.x >> 6)] = s2; }
        __syncthreads();
        float ts = red[0] + red[1] + red[2] + red[3];
        float t2 = red[4] + red[5] + red[6] + red[7];
        float mu = ts * (1.0f / CDIM);
        float var = t2 * (1.0f / CDIM) - mu * mu;
        float rstd = rsqrtf(var + 1e-5f);
        signed char* orow = a1 + (size_t)row * CDIM;
        float vv[3] = {v0, v1, v2};
#pragma unroll
        for (int p = 0; p < 3; p++) {
            int i = threadIdx.x + p * 256;
            float val = (vv[p] - mu) * rstd * ln1_g[i] + ln1_b[i];
            orow[i] = (val >= 0.f) ? 1 : -1;
        }
        return;
    }

    // ---- weight sign (+ alpha) ----
    const float* w; signed char* ws; float* alpha; int K; bool perm; int row;
    if (blk < 768)       { w = w_proj; ws = wproj_s; alpha = a_proj; K = CDIM; perm = true;  row = blk; }
    else if (blk < 3840) { w = w_fc1;  ws = wfc1_s;  alpha = a_fc1;  K = CDIM; perm = false; row = blk - 768; }
    else if (blk < 4608) { w = w_fc2;  ws = wfc2_s;  alpha = a_fc2;  K = HIDD; perm = true;  row = blk - 3840; }
    else                 { w = w_qkv;  ws = wqkv_s;  alpha = nullptr; K = CDIM; perm = false; row = blk - 4608; }

    const float* wr = w + (size_t)row * K;
    signed char* wsr = ws + (size_t)row * K;
    float s = 0.f;
    for (int i = threadIdx.x; i < K; i += 256) {
        float v = wr[i];
        int ip = perm ? ((i & ~63) | (((i & 15) << 2) | ((i >> 4) & 3))) : i;
        wsr[ip] = (v >= 0.f) ? 1 : -1;
        s += fabsf(v);
    }
    if (alpha) {
        for (int off = 32; off > 0; off >>= 1) s += __shfl_down(s, off);
        if ((threadIdx.x & 63) == 0) red[threadIdx.x >> 6] = s;
        __syncthreads();
        if (threadIdx.x == 0) alpha[row] = (red[0] + red[1] + red[2] + red[3]) / (float)K;
    }
}

// LayerNorm over 768 (bf16 x1 input) -> per-row i8 quant; rowscale[row] = rowmax/127
__global__ void __launch_bounds__(256) ln2q_kernel(const unsigned short* __restrict__ x, const float* __restrict__ g,
                                                   const float* __restrict__ b, signed char* __restrict__ out,
                                                   float* __restrict__ rowscale) {
    int row = blockIdx.x;
    const unsigned short* xr = x + (size_t)row * CDIM;
    float v0 = bf16_to_f32(xr[threadIdx.x]);
    float v1 = bf16_to_f32(xr[threadIdx.x + 256]);
    float v2 = bf16_to_f32(xr[threadIdx.x + 512]);
    float s = v0 + v1 + v2, s2 = v0 * v0 + v1 * v1 + v2 * v2;
    for (int off = 32; off > 0; off >>= 1) { s += __shfl_down(s, off); s2 += __shfl_down(s2, off); }
    __shared__ float red[8];
    __shared__ float redm[4];
    if ((threadIdx.x & 63) == 0) { red[threadIdx.x >> 6] = s; red[4 + (threadIdx.x >> 6)] = s2; }
    __syncthreads();
    float ts = red[0] + red[1] + red[2] + red[3];
    float t2 = red[4] + red[5] + red[6] + red[7];
    float mu = ts * (1.0f / CDIM);
    float var = t2 * (1.0f / CDIM) - mu * mu;
    float rstd = rsqrtf(var + 1e-5f);
    float a0 = (v0 - mu) * rstd * g[threadIdx.x] + b[threadIdx.x];
    float a1 = (v1 - mu) * rstd * g[threadIdx.x + 256] + b[threadIdx.x + 256];
    float a2v = (v2 - mu) * rstd * g[threadIdx.x + 512] + b[threadIdx.x + 512];
    float mx = fmaxf(fabsf(a0), fmaxf(fabsf(a1), fabsf(a2v)));
    for (int off = 32; off > 0; off >>= 1) mx = fmaxf(mx, __shfl_down(mx, off));
    if ((threadIdx.x & 63) == 0) redm[threadIdx.x >> 6] = mx;
    __syncthreads();
    float rmax = fmaxf(fmaxf(redm[0], redm[1]), fmaxf(redm[2], redm[3]));
    rmax = fmaxf(rmax, 1e-20f);
    float inv = 127.f / rmax;
    signed char* orow = out + (size_t)row * CDIM;
    orow[threadIdx.x]       = (signed char)__float2int_rn(a0 * inv);
    orow[threadIdx.x + 256] = (signed char)__float2int_rn(a1 * inv);
    orow[threadIdx.x + 512] = (signed char)__float2int_rn(a2v * inv);
    if (threadIdx.x == 0) rowscale[row] = rmax * (1.f / 127.f);
}

// ---------- i8 GEMM 256x128, 8 waves (4m x 2n): QKV / GELU epilogues ----------
enum { EPI_GELU = 2, EPI_QKV = 3 };
#define MSCALE_INV 16.0f

template<int EPI>
__global__ void __launch_bounds__(512, 4) gemm_i8(
    const signed char* __restrict__ A, const signed char* __restrict__ B,
    int M, int N, int K,
    const float* __restrict__ alpha, const float* __restrict__ bias,
    const float* __restrict__ rowscale,
    signed char* __restrict__ outB, signed char* __restrict__ vtB)
{
    __shared__ __align__(16) char lds_raw[3 * (256 + 128) * 64];   // 72 KB -> 2 blocks/CU
    auto As = (signed char (*)[256][64])lds_raw;
    auto Bs = (signed char (*)[128][64])(lds_raw + 3 * 256 * 64);

    const int tid = threadIdx.x, ln = tid & 63, w = tid >> 6;
    const int wm = w >> 1, wn = w & 1;                 // 4m x 2n waves
    const int lq = ln & 15, khi = ln >> 4;

    const int nwg = gridDim.x * gridDim.y;
    const int id = blockIdx.y * gridDim.x + blockIdx.x;
    const int nid = (id & 7) * (nwg >> 3) + (id >> 3);
    const int bxs = nid % gridDim.x, bys = nid / gridDim.x;
    const int bm = bys * 256, bn = bxs * 128;

    const i32x4 iz = {0, 0, 0, 0};
    i32x4 acc[4][4];
#pragma unroll
    for (int m = 0; m < 4; m++)
#pragma unroll
        for (int n = 0; n < 4; n++) acc[m][n] = iz;

    const int srow = tid >> 2, scol = (tid & 3) * 16;
    const int ssrc = ((tid & 3) ^ ((srow >> 1) & 3)) * 16;
    const int sa = 16 * (khi ^ ((lq >> 1) & 3));

    auto STAGE = [&](int p, int k0) {
        gload_lds16(A + (size_t)(bm + srow) * K + k0 + ssrc, &As[p][srow][scol]);
        gload_lds16(A + (size_t)(bm + 128 + srow) * K + k0 + ssrc, &As[p][128 + srow][scol]);
        gload_lds16(B + (size_t)(bn + srow) * K + k0 + ssrc, &Bs[p][srow][scol]);
    };
    auto COMPUTE = [&](int p, bool prefetch, int knext) {
        i32x4 aF[4], bF[4];
#pragma unroll
        for (int m = 0; m < 4; m++) aF[m] = *(const i32x4*)&As[p][wm * 64 + m * 16 + lq][sa];
#pragma unroll
        for (int n = 0; n < 4; n++) bF[n] = *(const i32x4*)&Bs[p][wn * 64 + n * 16 + lq][sa];
        if (prefetch) STAGE((p + 2) % 3, knext);
        __builtin_amdgcn_s_setprio(1);
#pragma unroll
        for (int m = 0; m < 4; m++)
#pragma unroll
            for (int n = 0; n < 4; n++)
                acc[m][n] = __builtin_amdgcn_mfma_i32_16x16x64_i8(aF[m], bF[n], acc[m][n], 0, 0, 0);
        __builtin_amdgcn_s_setprio(0);
    };

    const int nst = K >> 6;            // 12
    STAGE(0, 0);
    STAGE(1, 64);
#pragma unroll 1
    for (int t = 0; t < nst - 1; t++) {
        asm volatile("s_waitcnt vmcnt(3)" ::: "memory");
        asm volatile("s_waitcnt lgkmcnt(0)" ::: "memory");
        __builtin_amdgcn_s_barrier();
        COMPUTE(t % 3, t + 2 < nst, (t + 2) << 6);
    }
    asm volatile("s_waitcnt vmcnt(0)" ::: "memory");
    asm volatile("s_waitcnt lgkmcnt(0)" ::: "memory");
    __builtin_amdgcn_s_barrier();
    COMPUTE((nst - 1) % 3, false, 0);

    const int r0 = bm + wm * 64;
    const int c0 = bn + wn * 64;       // wave's 64-col group

    if constexpr (EPI == EPI_GELU) {
        float al[4], bi[4];
#pragma unroll
        for (int n = 0; n < 4; n++) {
            al[n] = alpha[c0 + n * 16 + lq];
            bi[n] = bias[c0 + n * 16 + lq];
        }
#pragma unroll
        for (int m = 0; m < 4; m++)
#pragma unroll
            for (int i = 0; i < 4; i++) {
                int r = r0 + m * 16 + khi * 4 + i;
                float rs = rowscale[r];
                unsigned pk = 0;
#pragma unroll
                for (int n = 0; n < 4; n++) {
                    float t = al[n] * ((float)acc[m][n][i] * rs) + bi[n];
                    float y2 = 1.5957691f * t + 0.07135481f * t * t * t;
                    float ge = t * __builtin_amdgcn_rcpf(1.0f + __expf(-y2));
                    float qf = fminf(fmaxf(ge * MSCALE_INV, -127.f), 127.f);
                    pk |= (unsigned)(unsigned char)(signed char)__float2int_rn(qf) << (8 * n);
                }
                *(unsigned*)(outB + (size_t)r * N + c0 + lq * 4) = pk;
            }
    } else {  // EPI_QKV
        if (c0 < 1536) {
#pragma unroll
            for (int m = 0; m < 4; m++)
#pragma unroll
                for (int i = 0; i < 4; i++) {
                    int r = r0 + m * 16 + khi * 4 + i;
                    unsigned pk = 0;
#pragma unroll
                    for (int n = 0; n < 4; n++)
                        pk |= (unsigned)(unsigned char)(signed char)((acc[m][n][i] >= 0) ? 1 : -1) << (8 * n);
                    *(unsigned*)(outB + (size_t)r * 1536 + c0 + lq * 4) = pk;
                }
        } else {
#pragma unroll
            for (int m = 0; m < 4; m++)
#pragma unroll
                for (int n = 0; n < 4; n++) {
                    int cg = c0 + n * 16 + lq - 1536;
                    int hh = cg >> 6, dd = cg & 63;
                    int rb = r0 + m * 16 + khi * 4;
                    unsigned pk = 0;
#pragma unroll
                    for (int i = 0; i < 4; i++)
                        pk |= (unsigned)(unsigned char)(signed char)((acc[m][n][i] >= 0) ? 1 : -1) << (8 * i);
                    *(unsigned*)(vtB + (((size_t)(rb >> 10) * NHEAD + hh) * 64 + dd) * SEQL + (rb & 1023)) = pk;
                }
        }
    }
}

// ---------- 128x64 RESID GEMM (proj / fc2) ----------
// 3-buffer counted-vmcnt pipeline + T14 preloaded epilogue operands.
// FINAL=false (proj): resid = x (f32), output x1 as bf16.
// FINAL=true  (fc2): resid = x1 (bf16), output d_out f32.
template<bool FINAL>
__global__ void __launch_bounds__(256) gemm_resid(
    const signed char* __restrict__ A, const signed char* __restrict__ B,
    int N, int K,
    const float* __restrict__ alpha, const float* __restrict__ bias,
    const float* __restrict__ ls,
    const float* __restrict__ residF, const unsigned short* __restrict__ residH,
    float ascale,
    float* __restrict__ outF, unsigned short* __restrict__ outH)
{
    __shared__ __align__(16) char lds_raw[3 * (128 + 64) * 64];   // 36 KB; epi Cf 128x68 f32 fits
    auto As = (signed char (*)[128][64])lds_raw;
    auto Bs = (signed char (*)[64][64])(lds_raw + 3 * 128 * 64);

    const int tid = threadIdx.x, ln = tid & 63, w = tid >> 6;
    const int wm = w >> 1, wn = w & 1;
    const int lq = ln & 15, khi = ln >> 4;

    const int nwg = gridDim.x * gridDim.y;
    const int id = blockIdx.y * gridDim.x + blockIdx.x;
    const int nid = (id & 7) * (nwg >> 3) + (id >> 3);
    const int bxs = nid % gridDim.x, bys = nid / gridDim.x;
    const int bm = bys * 128, bn = bxs * 64;

    // ---- T14 preload: epilogue operands issued before any staging ----
    const int erow = tid >> 4;           // 0..15
    const int ec4 = (tid & 15) * 4;
    f32x4 a4 = *(const f32x4*)&alpha[bn + ec4];
    f32x4 b4 = *(const f32x4*)&bias[bn + ec4];
    f32x4 l4 = *(const f32x4*)&ls[bn + ec4];
    f32x4 rF[8];
    us4 rH[8];
#pragma unroll
    for (int p = 0; p < 8; p++) {
        size_t g = (size_t)(bm + p * 16 + erow) * N + bn + ec4;
        if constexpr (FINAL) rH[p] = *(const us4*)&residH[g];
        else                 rF[p] = *(const f32x4*)&residF[g];
    }

    const i32x4 iz = {0, 0, 0, 0};
    i32x4 acc[4][2];
#pragma unroll
    for (int m = 0; m < 4; m++)
#pragma unroll
        for (int n = 0; n < 2; n++) acc[m][n] = iz;

    const int srow = tid >> 2, scol = (tid & 3) * 16;
    const int ssrc = ((tid & 3) ^ ((srow >> 1) & 3)) * 16;
    const int sa = 16 * (khi ^ ((lq >> 1) & 3));

    auto STAGE = [&](int p, int k0) {
        gload_lds16(A + (size_t)(bm + srow) * K + k0 + ssrc, &As[p][srow][scol]);
        gload_lds16(A + (size_t)(bm + 64 + srow) * K + k0 + ssrc, &As[p][64 + srow][scol]);
        gload_lds16(B + (size_t)(bn + srow) * K + k0 + ssrc, &Bs[p][srow][scol]);
    };
    auto COMPUTE = [&](int p, bool prefetch, int knext) {
        i32x4 aF[4], bF[2];
#pragma unroll
        for (int m = 0; m < 4; m++) aF[m] = *(const i32x4*)&As[p][wm * 64 + m * 16 + lq][sa];
#pragma unroll
        for (int n = 0; n < 2; n++) bF[n] = *(const i32x4*)&Bs[p][wn * 32 + n * 16 + lq][sa];
        if (prefetch) STAGE((p + 2) % 3, knext);
        __builtin_amdgcn_s_setprio(1);
#pragma unroll
        for (int m = 0; m < 4; m++)
#pragma unroll
            for (int n = 0; n < 2; n++)
                acc[m][n] = __builtin_amdgcn_mfma_i32_16x16x64_i8(aF[m], bF[n], acc[m][n], 0, 0, 0);
        __builtin_amdgcn_s_setprio(0);
    };

    const int nst = K >> 6;            // 12 or 48
    STAGE(0, 0);
    STAGE(1, 64);
#pragma unroll 1
    for (int t = 0; t < nst - 1; t++) {
        asm volatile("s_waitcnt vmcnt(3)" ::: "memory");   // stage t done (preloads retire first)
        asm volatile("s_waitcnt lgkmcnt(0)" ::: "memory");
        __builtin_amdgcn_s_barrier();
        COMPUTE(t % 3, t + 2 < nst, (t + 2) << 6);
    }
    asm volatile("s_waitcnt vmcnt(0)" ::: "memory");
    asm volatile("s_waitcnt lgkmcnt(0)" ::: "memory");
    __builtin_amdgcn_s_barrier();
    COMPUTE((nst - 1) % 3, false, 0);

    // ---- epilogue: LDS transpose -> pure FMA + coalesced store (resid in regs) ----
    __syncthreads();
    float (*Cf)[68] = (float (*)[68])lds_raw;
#pragma unroll
    for (int m = 0; m < 4; m++)
#pragma unroll
        for (int n = 0; n < 2; n++)
#pragma unroll
            for (int i = 0; i < 4; i++)
                Cf[wm * 64 + m * 16 + khi * 4 + i][wn * 32 + n * 16 + lq] =
                    (float)acc[m][n][i] * ascale;
    __syncthreads();
#pragma unroll
    for (int p = 0; p < 8; p++) {
        int row = p * 16 + erow;
        f32x4 v4 = *(const f32x4*)&Cf[row][ec4];
        size_t g = (size_t)(bm + row) * N + bn + ec4;
        if constexpr (FINAL) {
            f32x4 r;
            r.x = bf16_to_f32(rH[p].x); r.y = bf16_to_f32(rH[p].y);
            r.z = bf16_to_f32(rH[p].z); r.w = bf16_to_f32(rH[p].w);
            f32x4 o4 = r + l4 * (a4 * v4 + b4);
            *(f32x4*)&outF[g] = o4;
        } else {
            f32x4 o4 = rF[p] + l4 * (a4 * v4 + b4);
            us4 h;
            h.x = f32_to_bf16(o4.x); h.y = f32_to_bf16(o4.y);
            h.z = f32_to_bf16(o4.z); h.w = f32_to_bf16(o4.w);
            *(us4*)&outH[g] = h;
        }
    }
}

// ---------- binary attention v2 (exact i8) ----------
__global__ void __launch_bounds__(256) attn_v2(const signed char* __restrict__ qk,
                                               const signed char* __restrict__ vt,
                                               signed char* __restrict__ a2) {
    const int id = blockIdx.x;                       // 0..767
    const int nid = (id & 7) * 96 + (id >> 3);
    const int bh = nid >> 3, qb = nid & 7;
    const int b = bh / NHEAD, h = bh % NHEAD;
    const int tid = threadIdx.x, ln = tid & 63, w = tid >> 6;
    const int lq = ln & 15, khi = ln >> 4;

    __shared__ signed char Ks[64][80];
    __shared__ signed char Vts[64][80];
    __shared__ signed char Pw[4][32][80];

    const size_t tokbase = (size_t)b * SEQL;
    const int q0 = qb * 128 + w * 32;
    const int str = tid >> 2, stc = (tid & 3) * 16;
    const size_t vtrow = ((size_t)bh * 64 + str) * SEQL;

    i32x4 qfrag[2];
#pragma unroll
    for (int qf = 0; qf < 2; qf++)
        qfrag[qf] = *(const i32x4*)(qk + (tokbase + q0 + qf * 16 + lq) * 1536 + h * 64 + khi * 16);

    const i32x4 iz = {0, 0, 0, 0};
    i32x4 o[2][4];
#pragma unroll
    for (int qf = 0; qf < 2; qf++)
#pragma unroll
        for (int df = 0; df < 4; df++) o[qf][df] = iz;

    auto LOADJ = [&](int j, sc16& kr, sc16& vr) {
        kr = *(const sc16*)(qk + (tokbase + j * 64 + str) * 1536 + 768 + h * 64 + stc);
        vr = *(const sc16*)(vt + vtrow + j * 64 + stc);
    };
    auto STORE = [&](const sc16& kr, const sc16& vr) {
        *(sc16*)&Ks[str][stc] = kr;
        *(sc16*)&Vts[str][stc] = vr;
    };
    auto COMPUTE = [&]() {
        i32x4 kfrag[4];
#pragma unroll
        for (int kf = 0; kf < 4; kf++)
            kfrag[kf] = *(const i32x4*)&Ks[kf * 16 + lq][khi * 16];
#pragma unroll
        for (int kf = 0; kf < 4; kf++) {
#pragma unroll
            for (int qf = 0; qf < 2; qf++) {
                i32x4 st = __builtin_amdgcn_mfma_i32_16x16x64_i8(kfrag[kf], qfrag[qf], iz, 0, 0, 0);
                unsigned pb = (st[0] > 0 ? 1u : 0u) | (st[1] > 0 ? 0x100u : 0u) |
                              (st[2] > 0 ? 0x10000u : 0u) | (st[3] > 0 ? 0x1000000u : 0u);
                *(unsigned*)&Pw[w][qf * 16 + lq][kf * 16 + khi * 4] = pb;
            }
        }
        i32x4 pa[2];
#pragma unroll
        for (int qf = 0; qf < 2; qf++)
            pa[qf] = *(const i32x4*)&Pw[w][qf * 16 + lq][khi * 16];
#pragma unroll
        for (int df = 0; df < 4; df++) {
            i32x4 vfr = *(const i32x4*)&Vts[df * 16 + lq][khi * 16];
#pragma unroll
            for (int qf = 0; qf < 2; qf++)
                o[qf][df] = __builtin_amdgcn_mfma_i32_16x16x64_i8(pa[qf], vfr, o[qf][df], 0, 0, 0);
        }
    };

    sc16 ka, va, kb, vb;
    LOADJ(0, ka, va);
#pragma unroll 1
    for (int jj = 0; jj < 16; jj += 2) {
        __syncthreads();
        STORE(ka, va);
        __syncthreads();
        LOADJ(jj + 1, kb, vb);
        COMPUTE();
        __syncthreads();
        STORE(kb, vb);
        __syncthreads();
        if (jj + 2 < 16) LOADJ(jj + 2, ka, va);
        COMPUTE();
    }

    // epilogue: pi-packed u32: a2[token][h*64 + lq*4 + df] = sign(O[.][df*16+lq])
#pragma unroll
    for (int qf = 0; qf < 2; qf++)
#pragma unroll
        for (int i = 0; i < 4; i++) {
            int qrow = q0 + qf * 16 + khi * 4 + i;
            unsigned pk = 0;
#pragma unroll
            for (int df = 0; df < 4; df++)
                pk |= (unsigned)(unsigned char)(signed char)((o[qf][df][i] >= 0) ? 1 : -1) << (8 * df);
            *(unsigned*)(a2 + (tokbase + qrow) * CDIM + h * 64 + lq * 4) = pk;
        }
}

// ---------- workspace layout (bytes) ----------
static const size_t OFF_WQKV  = 0;          // 2304*768   = 1769472
static const size_t OFF_WPROJ = 1769472;    // 768*768    = 589824
static const size_t OFF_WFC1  = 2359296;    // 3072*768   = 2359296
static const size_t OFF_WFC2  = 4718592;    // 768*3072   = 2359296
static const size_t OFF_APROJ = 7077888;    // 768*4
static const size_t OFF_AFC1  = 7080960;    // 3072*4
static const size_t OFF_AFC2  = 7093248;    // 768*4
static const size_t OFF_H2SC  = 7096320;    // 8192*4
static const size_t OFF_QK    = 7129088;    // 8192*1536  = 12582912 (dead after attn)
static const size_t OFF_VT    = 19712000;   // 96*64*1024 = 6291456  (dead after attn)
static const size_t OFF_A1    = 26003456;   // 8192*768   = 6291456
static const size_t OFF_A2    = 32294912;   // 8192*768   = 6291456
static const size_t OFF_M1    = 38586368;   // 8192*3072  = 25165824
static const size_t OFF_H2    = 63752192;   // 8192*768   = 6291456
// x1b (bf16, 12582912 B) aliases OFF_QK: qk dead when proj runs.
static const size_t OFF_X1B   = OFF_QK;
// total = 70043648 bytes

extern "C" void kernel_launch(void* const* d_in, const int* in_sizes, int n_in,
                              void* d_out, int out_size, void* d_ws, size_t ws_size,
                              hipStream_t stream) {
    const float* x      = (const float*)d_in[0];
    const float* ln1_g  = (const float*)d_in[1];
    const float* ln1_b  = (const float*)d_in[2];
    const float* w_qkv  = (const float*)d_in[3];
    const float* w_proj = (const float*)d_in[4];
    const float* b_proj = (const float*)d_in[5];
    const float* ls1_g  = (const float*)d_in[6];
    const float* ln2_g  = (const float*)d_in[7];
    const float* ln2_b  = (const float*)d_in[8];
    const float* w_fc1  = (const float*)d_in[9];
    const float* b_fc1  = (const float*)d_in[10];
    const float* w_fc2  = (const float*)d_in[11];
    const float* b_fc2  = (const float*)d_in[12];
    const float* ls2_g  = (const float*)d_in[13];
    float* out = (float*)d_out;

    char* ws = (char*)d_ws;
    signed char* wqkv_s  = (signed char*)(ws + OFF_WQKV);
    signed char* wproj_s = (signed char*)(ws + OFF_WPROJ);
    signed char* wfc1_s  = (signed char*)(ws + OFF_WFC1);
    signed char* wfc2_s  = (signed char*)(ws + OFF_WFC2);
    float* a_proj  = (float*)(ws + OFF_APROJ);
    float* a_fc1   = (float*)(ws + OFF_AFC1);
    float* a_fc2   = (float*)(ws + OFF_AFC2);
    float* h2scale = (float*)(ws + OFF_H2SC);
    signed char* qk   = (signed char*)(ws + OFF_QK);
    signed char* vt   = (signed char*)(ws + OFF_VT);
    signed char* a1   = (signed char*)(ws + OFF_A1);
    signed char* a2   = (signed char*)(ws + OFF_A2);
    signed char* m1   = (signed char*)(ws + OFF_M1);
    signed char* h2   = (signed char*)(ws + OFF_H2);
    unsigned short* x1b = (unsigned short*)(ws + OFF_X1B);

    // fused front-end: all weight prep + LN1 in one dispatch
    prep_all<<<15104, 256, 0, stream>>>(
        w_proj, w_fc1, w_fc2, w_qkv,
        wproj_s, wfc1_s, wfc2_s, wqkv_s,
        a_proj, a_fc1, a_fc2,
        x, ln1_g, ln1_b, a1);

    // QKV: sign(a1 @ wqkv^T); Q,K -> qk (pi-packed), V -> vt transposed
    gemm_i8<EPI_QKV><<<dim3(NQKV / 128, NTOK / 256), 512, 0, stream>>>(
        a1, wqkv_s, NTOK, NQKV, CDIM, nullptr, nullptr, nullptr, qk, vt);

    // binary attention -> sign(O) (exact i8)
    attn_v2<<<768, 256, 0, stream>>>(qk, vt, a2);

    // proj + layerscale residual: x1(bf16) = x + ls1*(ap*acc + bp)
    gemm_resid<false><<<dim3(CDIM / 64, NTOK / 128), 256, 0, stream>>>(
        a2, wproj_s, CDIM, CDIM, a_proj, b_proj, ls1_g, x, nullptr, 1.0f, nullptr, x1b);

    // LN2 (bf16 x1) + per-row i8 quant
    ln2q_kernel<<<NTOK, 256, 0, stream>>>(x1b, ln2_g, ln2_b, h2, h2scale);

    // fc1 + gelu -> fixed-scale i8 (pi-packed hidden layout)
    gemm_i8<EPI_GELU><<<dim3(HIDD / 128, NTOK / 256), 512, 0, stream>>>(
        h2, wfc1_s, NTOK, HIDD, CDIM, a_fc1, b_fc1, h2scale, m1, nullptr);

    // fc2 + final residual: out(f32) = x1 + ls2*(af2*acc/16 + bf2)
    gemm_resid<true><<<dim3(CDIM / 64, NTOK / 128), 256, 0, stream>>>(
        m1, wfc2_s, CDIM, HIDD, a_fc2, b_fc2, ls2_g, nullptr, x1b, 1.0f / MSCALE_INV, out, nullptr);
}

// Round 14
// 157.244 us; speedup vs baseline: 1.5990x; 1.0019x over previous
//
#include <hip/hip_runtime.h>

// ---- problem constants ----
#define NTOK 8192      // B*N = 8*1024
#define CDIM 768
#define HIDD 3072
#define NQKV 2304
#define SEQL 1024
#define NHEAD 12

typedef int i32x4 __attribute__((ext_vector_type(4)));
typedef float f32x4 __attribute__((ext_vector_type(4)));
typedef signed char sc16 __attribute__((ext_vector_type(16)));
typedef unsigned short us4 __attribute__((ext_vector_type(4)));

__device__ __forceinline__ unsigned short f32_to_bf16(float f) {
    unsigned int u = __float_as_uint(f);
    u += 0x7FFFu + ((u >> 16) & 1u);
    return (unsigned short)(u >> 16);
}
__device__ __forceinline__ float bf16_to_f32(unsigned short h) {
    return __uint_as_float(((unsigned)h) << 16);
}

// async global->LDS, 16B per lane. Dest must be wave-uniform base + lane*16.
__device__ __forceinline__ void gload_lds16(const void* g, void* l) {
    __builtin_amdgcn_global_load_lds(
        (const __attribute__((address_space(1))) unsigned int*)g,
        (__attribute__((address_space(3))) unsigned int*)l, 16, 0, 0);
}

// weight sign (+ optional alpha / pi-perm) helper, used by two fused kernels
__device__ __forceinline__ void sign_alpha_row(
    const float* __restrict__ w, signed char* __restrict__ ws,
    float* __restrict__ alpha, int K, bool perm, int row, float* red)
{
    const float* wr = w + (size_t)row * K;
    signed char* wsr = ws + (size_t)row * K;
    float s = 0.f;
    for (int i = threadIdx.x; i < K; i += 256) {
        float v = wr[i];
        int ip = perm ? ((i & ~63) | (((i & 15) << 2) | ((i >> 4) & 3))) : i;
        wsr[ip] = (v >= 0.f) ? 1 : -1;
        s += fabsf(v);
    }
    if (alpha) {
        for (int off = 32; off > 0; off >>= 1) s += __shfl_down(s, off);
        if ((threadIdx.x & 63) == 0) red[threadIdx.x >> 6] = s;
        __syncthreads();
        if (threadIdx.x == 0) alpha[row] = (red[0] + red[1] + red[2] + red[3]) / (float)K;
    }
}

// ============================================================================
// Front-end: wqkv sign + LN1(+sign) + bf16 copy of x.
// Blocks: [0,2304) wqkv rows | [2304,10496) LN1 rows.
// ============================================================================
__global__ void __launch_bounds__(256) prep_front(
    const float* __restrict__ w_qkv, signed char* __restrict__ wqkv_s,
    const float* __restrict__ x, const float* __restrict__ ln1_g,
    const float* __restrict__ ln1_b, signed char* __restrict__ a1,
    unsigned short* __restrict__ xb16)
{
    const int blk = blockIdx.x;
    __shared__ float red[8];

    if (blk < 2304) {
        sign_alpha_row(w_qkv, wqkv_s, nullptr, CDIM, false, blk, red);
        return;
    }
    // ---- LN1 + sign, and bf16 copy of x ----
    int row = blk - 2304;
    const float* xr = x + (size_t)row * CDIM;
    float v0 = xr[threadIdx.x], v1 = xr[threadIdx.x + 256], v2 = xr[threadIdx.x + 512];
    unsigned short* xbrow = xb16 + (size_t)row * CDIM;
    xbrow[threadIdx.x]       = f32_to_bf16(v0);
    xbrow[threadIdx.x + 256] = f32_to_bf16(v1);
    xbrow[threadIdx.x + 512] = f32_to_bf16(v2);
    float s = v0 + v1 + v2, s2 = v0 * v0 + v1 * v1 + v2 * v2;
    for (int off = 32; off > 0; off >>= 1) { s += __shfl_down(s, off); s2 += __shfl_down(s2, off); }
    if ((threadIdx.x & 63) == 0) { red[threadIdx.x >> 6] = s; red[4 + (threadIdx.x >> 6)] = s2; }
    __syncthreads();
    float ts = red[0] + red[1] + red[2] + red[3];
    float t2 = red[4] + red[5] + red[6] + red[7];
    float mu = ts * (1.0f / CDIM);
    float var = t2 * (1.0f / CDIM) - mu * mu;
    float rstd = rsqrtf(var + 1e-5f);
    signed char* orow = a1 + (size_t)row * CDIM;
    float vv[3] = {v0, v1, v2};
#pragma unroll
    for (int p = 0; p < 3; p++) {
        int i = threadIdx.x + p * 256;
        float val = (vv[p] - mu) * rstd * ln1_g[i] + ln1_b[i];
        orow[i] = (val >= 0.f) ? 1 : -1;
    }
}

// LayerNorm over 768 (bf16 x1 input) -> per-row i8 quant; rowscale[row] = rowmax/127
__global__ void __launch_bounds__(256) ln2q_kernel(const unsigned short* __restrict__ x, const float* __restrict__ g,
                                                   const float* __restrict__ b, signed char* __restrict__ out,
                                                   float* __restrict__ rowscale) {
    int row = blockIdx.x;
    const unsigned short* xr = x + (size_t)row * CDIM;
    float v0 = bf16_to_f32(xr[threadIdx.x]);
    float v1 = bf16_to_f32(xr[threadIdx.x + 256]);
    float v2 = bf16_to_f32(xr[threadIdx.x + 512]);
    float s = v0 + v1 + v2, s2 = v0 * v0 + v1 * v1 + v2 * v2;
    for (int off = 32; off > 0; off >>= 1) { s += __shfl_down(s, off); s2 += __shfl_down(s2, off); }
    __shared__ float red[8];
    __shared__ float redm[4];
    if ((threadIdx.x & 63) == 0) { red[threadIdx.x >> 6] = s; red[4 + (threadIdx.x >> 6)] = s2; }
    __syncthreads();
    float ts = red[0] + red[1] + red[2] + red[3];
    float t2 = red[4] + red[5] + red[6] + red[7];
    float mu = ts * (1.0f / CDIM);
    float var = t2 * (1.0f / CDIM) - mu * mu;
    float rstd = rsqrtf(var + 1e-5f);
    float a0 = (v0 - mu) * rstd * g[threadIdx.x] + b[threadIdx.x];
    float a1 = (v1 - mu) * rstd * g[threadIdx.x + 256] + b[threadIdx.x + 256];
    float a2v = (v2 - mu) * rstd * g[threadIdx.x + 512] + b[threadIdx.x + 512];
    float mx = fmaxf(fabsf(a0), fmaxf(fabsf(a1), fabsf(a2v)));
    for (int off = 32; off > 0; off >>= 1) mx = fmaxf(mx, __shfl_down(mx, off));
    if ((threadIdx.x & 63) == 0) redm[threadIdx.x >> 6] = mx;
    __syncthreads();
    float rmax = fmaxf(fmaxf(redm[0], redm[1]), fmaxf(redm[2], redm[3]));
    rmax = fmaxf(rmax, 1e-20f);
    float inv = 127.f / rmax;
    signed char* orow = out + (size_t)row * CDIM;
    orow[threadIdx.x]       = (signed char)__float2int_rn(a0 * inv);
    orow[threadIdx.x + 256] = (signed char)__float2int_rn(a1 * inv);
    orow[threadIdx.x + 512] = (signed char)__float2int_rn(a2v * inv);
    if (threadIdx.x == 0) rowscale[row] = rmax * (1.f / 127.f);
}

// ---------- i8 GEMM 256x128, 8 waves (4m x 2n): QKV / GELU epilogues ----------
enum { EPI_GELU = 2, EPI_QKV = 3 };
#define MSCALE_INV 16.0f

template<int EPI>
__global__ void __launch_bounds__(512, 4) gemm_i8(
    const signed char* __restrict__ A, const signed char* __restrict__ B,
    int M, int N, int K,
    const float* __restrict__ alpha, const float* __restrict__ bias,
    const float* __restrict__ rowscale,
    signed char* __restrict__ outB, signed char* __restrict__ vtB)
{
    __shared__ __align__(16) char lds_raw[3 * (256 + 128) * 64];   // 72 KB -> 2 blocks/CU
    auto As = (signed char (*)[256][64])lds_raw;
    auto Bs = (signed char (*)[128][64])(lds_raw + 3 * 256 * 64);

    const int tid = threadIdx.x, ln = tid & 63, w = tid >> 6;
    const int wm = w >> 1, wn = w & 1;                 // 4m x 2n waves
    const int lq = ln & 15, khi = ln >> 4;

    const int nwg = gridDim.x * gridDim.y;
    const int id = blockIdx.y * gridDim.x + blockIdx.x;
    const int nid = (id & 7) * (nwg >> 3) + (id >> 3);
    const int bxs = nid % gridDim.x, bys = nid / gridDim.x;
    const int bm = bys * 256, bn = bxs * 128;

    const i32x4 iz = {0, 0, 0, 0};
    i32x4 acc[4][4];
#pragma unroll
    for (int m = 0; m < 4; m++)
#pragma unroll
        for (int n = 0; n < 4; n++) acc[m][n] = iz;

    const int srow = tid >> 2, scol = (tid & 3) * 16;
    const int ssrc = ((tid & 3) ^ ((srow >> 1) & 3)) * 16;
    const int sa = 16 * (khi ^ ((lq >> 1) & 3));

    auto STAGE = [&](int p, int k0) {
        gload_lds16(A + (size_t)(bm + srow) * K + k0 + ssrc, &As[p][srow][scol]);
        gload_lds16(A + (size_t)(bm + 128 + srow) * K + k0 + ssrc, &As[p][128 + srow][scol]);
        gload_lds16(B + (size_t)(bn + srow) * K + k0 + ssrc, &Bs[p][srow][scol]);
    };
    auto COMPUTE = [&](int p, bool prefetch, int knext) {
        i32x4 aF[4], bF[4];
#pragma unroll
        for (int m = 0; m < 4; m++) aF[m] = *(const i32x4*)&As[p][wm * 64 + m * 16 + lq][sa];
#pragma unroll
        for (int n = 0; n < 4; n++) bF[n] = *(const i32x4*)&Bs[p][wn * 64 + n * 16 + lq][sa];
        if (prefetch) STAGE((p + 2) % 3, knext);
        __builtin_amdgcn_s_setprio(1);
#pragma unroll
        for (int m = 0; m < 4; m++)
#pragma unroll
            for (int n = 0; n < 4; n++)
                acc[m][n] = __builtin_amdgcn_mfma_i32_16x16x64_i8(aF[m], bF[n], acc[m][n], 0, 0, 0);
        __builtin_amdgcn_s_setprio(0);
    };

    const int nst = K >> 6;            // 12
    STAGE(0, 0);
    STAGE(1, 64);
#pragma unroll 1
    for (int t = 0; t < nst - 1; t++) {
        asm volatile("s_waitcnt vmcnt(3)" ::: "memory");
        asm volatile("s_waitcnt lgkmcnt(0)" ::: "memory");
        __builtin_amdgcn_s_barrier();
        COMPUTE(t % 3, t + 2 < nst, (t + 2) << 6);
    }
    asm volatile("s_waitcnt vmcnt(0)" ::: "memory");
    asm volatile("s_waitcnt lgkmcnt(0)" ::: "memory");
    __builtin_amdgcn_s_barrier();
    COMPUTE((nst - 1) % 3, false, 0);

    const int r0 = bm + wm * 64;
    const int c0 = bn + wn * 64;       // wave's 64-col group

    if constexpr (EPI == EPI_GELU) {
        float al[4], bi[4];
#pragma unroll
        for (int n = 0; n < 4; n++) {
            al[n] = alpha[c0 + n * 16 + lq];
            bi[n] = bias[c0 + n * 16 + lq];
        }
#pragma unroll
        for (int m = 0; m < 4; m++)
#pragma unroll
            for (int i = 0; i < 4; i++) {
                int r = r0 + m * 16 + khi * 4 + i;
                float rs = rowscale[r];
                unsigned pk = 0;
#pragma unroll
                for (int n = 0; n < 4; n++) {
                    float t = al[n] * ((float)acc[m][n][i] * rs) + bi[n];
                    float y2 = 1.5957691f * t + 0.07135481f * t * t * t;
                    float ge = t * __builtin_amdgcn_rcpf(1.0f + __expf(-y2));
                    float qf = fminf(fmaxf(ge * MSCALE_INV, -127.f), 127.f);
                    pk |= (unsigned)(unsigned char)(signed char)__float2int_rn(qf) << (8 * n);
                }
                *(unsigned*)(outB + (size_t)r * N + c0 + lq * 4) = pk;
            }
    } else {  // EPI_QKV
        if (c0 < 1536) {
#pragma unroll
            for (int m = 0; m < 4; m++)
#pragma unroll
                for (int i = 0; i < 4; i++) {
                    int r = r0 + m * 16 + khi * 4 + i;
                    unsigned pk = 0;
#pragma unroll
                    for (int n = 0; n < 4; n++)
                        pk |= (unsigned)(unsigned char)(signed char)((acc[m][n][i] >= 0) ? 1 : -1) << (8 * n);
                    *(unsigned*)(outB + (size_t)r * 1536 + c0 + lq * 4) = pk;
                }
        } else {
#pragma unroll
            for (int m = 0; m < 4; m++)
#pragma unroll
                for (int n = 0; n < 4; n++) {
                    int cg = c0 + n * 16 + lq - 1536;
                    int hh = cg >> 6, dd = cg & 63;
                    int rb = r0 + m * 16 + khi * 4;
                    unsigned pk = 0;
#pragma unroll
                    for (int i = 0; i < 4; i++)
                        pk |= (unsigned)(unsigned char)(signed char)((acc[m][n][i] >= 0) ? 1 : -1) << (8 * i);
                    *(unsigned*)(vtB + (((size_t)(rb >> 10) * NHEAD + hh) * 64 + dd) * SEQL + (rb & 1023)) = pk;
                }
        }
    }
}

// ---------- 128x64 RESID GEMM (proj / fc2) ----------
// 3-buffer counted-vmcnt pipeline + T14 preloaded epilogue operands.
// resid is always bf16. OUTF32=false (proj): output x1 bf16; true (fc2): f32.
template<bool OUTF32>
__global__ void __launch_bounds__(256) gemm_resid(
    const signed char* __restrict__ A, const signed char* __restrict__ B,
    int N, int K,
    const float* __restrict__ alpha, const float* __restrict__ bias,
    const float* __restrict__ ls, const unsigned short* __restrict__ residH,
    float ascale,
    float* __restrict__ outF, unsigned short* __restrict__ outH)
{
    __shared__ __align__(16) char lds_raw[3 * (128 + 64) * 64];   // 36 KB; epi Cf 128x68 f32 fits
    auto As = (signed char (*)[128][64])lds_raw;
    auto Bs = (signed char (*)[64][64])(lds_raw + 3 * 128 * 64);

    const int tid = threadIdx.x, ln = tid & 63, w = tid >> 6;
    const int wm = w >> 1, wn = w & 1;
    const int lq = ln & 15, khi = ln >> 4;

    const int nwg = gridDim.x * gridDim.y;
    const int id = blockIdx.y * gridDim.x + blockIdx.x;
    const int nid = (id & 7) * (nwg >> 3) + (id >> 3);
    const int bxs = nid % gridDim.x, bys = nid / gridDim.x;
    const int bm = bys * 128, bn = bxs * 64;

    // ---- T14 preload: epilogue operands issued before any staging ----
    const int erow = tid >> 4;           // 0..15
    const int ec4 = (tid & 15) * 4;
    f32x4 a4 = *(const f32x4*)&alpha[bn + ec4];
    f32x4 b4 = *(const f32x4*)&bias[bn + ec4];
    f32x4 l4 = *(const f32x4*)&ls[bn + ec4];
    us4 rH[8];
#pragma unroll
    for (int p = 0; p < 8; p++) {
        size_t g = (size_t)(bm + p * 16 + erow) * N + bn + ec4;
        rH[p] = *(const us4*)&residH[g];
    }

    const i32x4 iz = {0, 0, 0, 0};
    i32x4 acc[4][2];
#pragma unroll
    for (int m = 0; m < 4; m++)
#pragma unroll
        for (int n = 0; n < 2; n++) acc[m][n] = iz;

    const int srow = tid >> 2, scol = (tid & 3) * 16;
    const int ssrc = ((tid & 3) ^ ((srow >> 1) & 3)) * 16;
    const int sa = 16 * (khi ^ ((lq >> 1) & 3));

    auto STAGE = [&](int p, int k0) {
        gload_lds16(A + (size_t)(bm + srow) * K + k0 + ssrc, &As[p][srow][scol]);
        gload_lds16(A + (size_t)(bm + 64 + srow) * K + k0 + ssrc, &As[p][64 + srow][scol]);
        gload_lds16(B + (size_t)(bn + srow) * K + k0 + ssrc, &Bs[p][srow][scol]);
    };
    auto COMPUTE = [&](int p, bool prefetch, int knext) {
        i32x4 aF[4], bF[2];
#pragma unroll
        for (int m = 0; m < 4; m++) aF[m] = *(const i32x4*)&As[p][wm * 64 + m * 16 + lq][sa];
#pragma unroll
        for (int n = 0; n < 2; n++) bF[n] = *(const i32x4*)&Bs[p][wn * 32 + n * 16 + lq][sa];
        if (prefetch) STAGE((p + 2) % 3, knext);
        __builtin_amdgcn_s_setprio(1);
#pragma unroll
        for (int m = 0; m < 4; m++)
#pragma unroll
            for (int n = 0; n < 2; n++)
                acc[m][n] = __builtin_amdgcn_mfma_i32_16x16x64_i8(aF[m], bF[n], acc[m][n], 0, 0, 0);
        __builtin_amdgcn_s_setprio(0);
    };

    const int nst = K >> 6;            // 12 or 48
    STAGE(0, 0);
    STAGE(1, 64);
#pragma unroll 1
    for (int t = 0; t < nst - 1; t++) {
        asm volatile("s_waitcnt vmcnt(3)" ::: "memory");   // stage t done (preloads retire first)
        asm volatile("s_waitcnt lgkmcnt(0)" ::: "memory");
        __builtin_amdgcn_s_barrier();
        COMPUTE(t % 3, t + 2 < nst, (t + 2) << 6);
    }
    asm volatile("s_waitcnt vmcnt(0)" ::: "memory");
    asm volatile("s_waitcnt lgkmcnt(0)" ::: "memory");
    __builtin_amdgcn_s_barrier();
    COMPUTE((nst - 1) % 3, false, 0);

    // ---- epilogue: LDS transpose -> pure FMA + coalesced store (resid in regs) ----
    __syncthreads();
    float (*Cf)[68] = (float (*)[68])lds_raw;
#pragma unroll
    for (int m = 0; m < 4; m++)
#pragma unroll
        for (int n = 0; n < 2; n++)
#pragma unroll
            for (int i = 0; i < 4; i++)
                Cf[wm * 64 + m * 16 + khi * 4 + i][wn * 32 + n * 16 + lq] =
                    (float)acc[m][n][i] * ascale;
    __syncthreads();
#pragma unroll
    for (int p = 0; p < 8; p++) {
        int row = p * 16 + erow;
        f32x4 v4 = *(const f32x4*)&Cf[row][ec4];
        size_t g = (size_t)(bm + row) * N + bn + ec4;
        f32x4 r;
        r.x = bf16_to_f32(rH[p].x); r.y = bf16_to_f32(rH[p].y);
        r.z = bf16_to_f32(rH[p].z); r.w = bf16_to_f32(rH[p].w);
        f32x4 o4 = r + l4 * (a4 * v4 + b4);
        if constexpr (OUTF32) {
            *(f32x4*)&outF[g] = o4;
        } else {
            us4 h;
            h.x = f32_to_bf16(o4.x); h.y = f32_to_bf16(o4.y);
            h.z = f32_to_bf16(o4.z); h.w = f32_to_bf16(o4.w);
            *(us4*)&outH[g] = h;
        }
    }
}

// ---------- binary attention (exact i8) + fused wproj/wfc1/wfc2 prep ----------
// Blocks [0,768): attention. [768,1536): wproj | [1536,4608): wfc1 |
// [4608,5376): wfc2 — fills CUs left idle by attention's small grid.
__global__ void __launch_bounds__(256) attn_prep(
    const signed char* __restrict__ qk, const signed char* __restrict__ vt,
    signed char* __restrict__ a2,
    const float* __restrict__ w_proj, const float* __restrict__ w_fc1,
    const float* __restrict__ w_fc2,
    signed char* __restrict__ wproj_s, signed char* __restrict__ wfc1_s,
    signed char* __restrict__ wfc2_s,
    float* __restrict__ a_proj, float* __restrict__ a_fc1, float* __restrict__ a_fc2)
{
    const int blk = blockIdx.x;
    if (blk >= 768) {
        __shared__ float red[4];
        if (blk < 1536)      sign_alpha_row(w_proj, wproj_s, a_proj, CDIM, true,  blk - 768, red);
        else if (blk < 4608) sign_alpha_row(w_fc1,  wfc1_s,  a_fc1,  CDIM, false, blk - 1536, red);
        else                 sign_alpha_row(w_fc2,  wfc2_s,  a_fc2,  HIDD, true,  blk - 4608, red);
        return;
    }

    const int id = blk;                              // 0..767
    const int nid = (id & 7) * 96 + (id >> 3);
    const int bh = nid >> 3, qb = nid & 7;
    const int b = bh / NHEAD, h = bh % NHEAD;
    const int tid = threadIdx.x, ln = tid & 63, w = tid >> 6;
    const int lq = ln & 15, khi = ln >> 4;

    __shared__ signed char Ks[64][80];
    __shared__ signed char Vts[64][80];
    __shared__ signed char Pw[4][32][80];

    const size_t tokbase = (size_t)b * SEQL;
    const int q0 = qb * 128 + w * 32;
    const int str = tid >> 2, stc = (tid & 3) * 16;
    const size_t vtrow = ((size_t)bh * 64 + str) * SEQL;

    i32x4 qfrag[2];
#pragma unroll
    for (int qf = 0; qf < 2; qf++)
        qfrag[qf] = *(const i32x4*)(qk + (tokbase + q0 + qf * 16 + lq) * 1536 + h * 64 + khi * 16);

    const i32x4 iz = {0, 0, 0, 0};
    i32x4 o[2][4];
#pragma unroll
    for (int qf = 0; qf < 2; qf++)
#pragma unroll
        for (int df = 0; df < 4; df++) o[qf][df] = iz;

    auto LOADJ = [&](int j, sc16& kr, sc16& vr) {
        kr = *(const sc16*)(qk + (tokbase + j * 64 + str) * 1536 + 768 + h * 64 + stc);
        vr = *(const sc16*)(vt + vtrow + j * 64 + stc);
    };
    auto STORE = [&](const sc16& kr, const sc16& vr) {
        *(sc16*)&Ks[str][stc] = kr;
        *(sc16*)&Vts[str][stc] = vr;
    };
    auto COMPUTE = [&]() {
        i32x4 kfrag[4];
#pragma unroll
        for (int kf = 0; kf < 4; kf++)
            kfrag[kf] = *(const i32x4*)&Ks[kf * 16 + lq][khi * 16];
#pragma unroll
        for (int kf = 0; kf < 4; kf++) {
#pragma unroll
            for (int qf = 0; qf < 2; qf++) {
                i32x4 st = __builtin_amdgcn_mfma_i32_16x16x64_i8(kfrag[kf], qfrag[qf], iz, 0, 0, 0);
                unsigned pb = (st[0] > 0 ? 1u : 0u) | (st[1] > 0 ? 0x100u : 0u) |
                              (st[2] > 0 ? 0x10000u : 0u) | (st[3] > 0 ? 0x1000000u : 0u);
                *(unsigned*)&Pw[w][qf * 16 + lq][kf * 16 + khi * 4] = pb;
            }
        }
        i32x4 pa[2];
#pragma unroll
        for (int qf = 0; qf < 2; qf++)
            pa[qf] = *(const i32x4*)&Pw[w][qf * 16 + lq][khi * 16];
#pragma unroll
        for (int df = 0; df < 4; df++) {
            i32x4 vfr = *(const i32x4*)&Vts[df * 16 + lq][khi * 16];
#pragma unroll
            for (int qf = 0; qf < 2; qf++)
                o[qf][df] = __builtin_amdgcn_mfma_i32_16x16x64_i8(pa[qf], vfr, o[qf][df], 0, 0, 0);
        }
    };

    sc16 ka, va, kb, vb;
    LOADJ(0, ka, va);
#pragma unroll 1
    for (int jj = 0; jj < 16; jj += 2) {
        __syncthreads();
        STORE(ka, va);
        __syncthreads();
        LOADJ(jj + 1, kb, vb);
        COMPUTE();
        __syncthreads();
        STORE(kb, vb);
        __syncthreads();
        if (jj + 2 < 16) LOADJ(jj + 2, ka, va);
        COMPUTE();
    }

    // epilogue: pi-packed u32: a2[token][h*64 + lq*4 + df] = sign(O[.][df*16+lq])
#pragma unroll
    for (int qf = 0; qf < 2; qf++)
#pragma unroll
        for (int i = 0; i < 4; i++) {
            int qrow = q0 + qf * 16 + khi * 4 + i;
            unsigned pk = 0;
#pragma unroll
            for (int df = 0; df < 4; df++)
                pk |= (unsigned)(unsigned char)(signed char)((o[qf][df][i] >= 0) ? 1 : -1) << (8 * df);
            *(unsigned*)(a2 + (tokbase + qrow) * CDIM + h * 64 + lq * 4) = pk;
        }
}

// ---------- workspace layout (bytes) ----------
static const size_t OFF_WQKV  = 0;          // 2304*768   = 1769472
static const size_t OFF_WPROJ = 1769472;    // 768*768    = 589824
static const size_t OFF_WFC1  = 2359296;    // 3072*768   = 2359296
static const size_t OFF_WFC2  = 4718592;    // 768*3072   = 2359296
static const size_t OFF_APROJ = 7077888;    // 768*4
static const size_t OFF_AFC1  = 7080960;    // 3072*4
static const size_t OFF_AFC2  = 7093248;    // 768*4
static const size_t OFF_H2SC  = 7096320;    // 8192*4
static const size_t OFF_QK    = 7129088;    // 8192*1536  = 12582912 (dead after attn)
static const size_t OFF_VT    = 19712000;   // 96*64*1024 = 6291456  (dead after attn)
static const size_t OFF_A1    = 26003456;   // 8192*768   = 6291456
static const size_t OFF_A2    = 32294912;   // 8192*768   = 6291456
static const size_t OFF_M1    = 38586368;   // 8192*3072  = 25165824
static const size_t OFF_H2    = 63752192;   // 8192*768   = 6291456
// x1b (bf16, 12582912) aliases OFF_QK: qk dead when proj writes x1b.
static const size_t OFF_X1B   = OFF_QK;
// xb16 (bf16 copy of x, 12582912) aliases OFF_M1: m1 written by fc1, after
// proj (the last reader of xb16).
static const size_t OFF_XB16  = OFF_M1;
// total = 70043648 bytes

extern "C" void kernel_launch(void* const* d_in, const int* in_sizes, int n_in,
                              void* d_out, int out_size, void* d_ws, size_t ws_size,
                              hipStream_t stream) {
    const float* x      = (const float*)d_in[0];
    const float* ln1_g  = (const float*)d_in[1];
    const float* ln1_b  = (const float*)d_in[2];
    const float* w_qkv  = (const float*)d_in[3];
    const float* w_proj = (const float*)d_in[4];
    const float* b_proj = (const float*)d_in[5];
    const float* ls1_g  = (const float*)d_in[6];
    const float* ln2_g  = (const float*)d_in[7];
    const float* ln2_b  = (const float*)d_in[8];
    const float* w_fc1  = (const float*)d_in[9];
    const float* b_fc1  = (const float*)d_in[10];
    const float* w_fc2  = (const float*)d_in[11];
    const float* b_fc2  = (const float*)d_in[12];
    const float* ls2_g  = (const float*)d_in[13];
    float* out = (float*)d_out;

    char* ws = (char*)d_ws;
    signed char* wqkv_s  = (signed char*)(ws + OFF_WQKV);
    signed char* wproj_s = (signed char*)(ws + OFF_WPROJ);
    signed char* wfc1_s  = (signed char*)(ws + OFF_WFC1);
    signed char* wfc2_s  = (signed char*)(ws + OFF_WFC2);
    float* a_proj  = (float*)(ws + OFF_APROJ);
    float* a_fc1   = (float*)(ws + OFF_AFC1);
    float* a_fc2   = (float*)(ws + OFF_AFC2);
    float* h2scale = (float*)(ws + OFF_H2SC);
    signed char* qk   = (signed char*)(ws + OFF_QK);
    signed char* vt   = (signed char*)(ws + OFF_VT);
    signed char* a1   = (signed char*)(ws + OFF_A1);
    signed char* a2   = (signed char*)(ws + OFF_A2);
    signed char* m1   = (signed char*)(ws + OFF_M1);
    signed char* h2   = (signed char*)(ws + OFF_H2);
    unsigned short* x1b  = (unsigned short*)(ws + OFF_X1B);
    unsigned short* xb16 = (unsigned short*)(ws + OFF_XB16);

    // front-end: wqkv sign + LN1+sign + bf16 copy of x (one dispatch)
    prep_front<<<2304 + NTOK, 256, 0, stream>>>(w_qkv, wqkv_s, x, ln1_g, ln1_b, a1, xb16);

    // QKV: sign(a1 @ wqkv^T); Q,K -> qk (pi-packed), V -> vt transposed
    gemm_i8<EPI_QKV><<<dim3(NQKV / 128, NTOK / 256), 512, 0, stream>>>(
        a1, wqkv_s, NTOK, NQKV, CDIM, nullptr, nullptr, nullptr, qk, vt);

    // binary attention (exact i8) + wproj/wfc1/wfc2 prep on idle CUs
    attn_prep<<<5376, 256, 0, stream>>>(qk, vt, a2,
                                        w_proj, w_fc1, w_fc2,
                                        wproj_s, wfc1_s, wfc2_s,
                                        a_proj, a_fc1, a_fc2);

    // proj + layerscale residual: x1(bf16) = x + ls1*(ap*acc + bp)  (resid = xb16)
    gemm_resid<false><<<dim3(CDIM / 64, NTOK / 128), 256, 0, stream>>>(
        a2, wproj_s, CDIM, CDIM, a_proj, b_proj, ls1_g, xb16, 1.0f, nullptr, x1b);

    // LN2 (bf16 x1) + per-row i8 quant
    ln2q_kernel<<<NTOK, 256, 0, stream>>>(x1b, ln2_g, ln2_b, h2, h2scale);

    // fc1 + gelu -> fixed-scale i8 (pi-packed hidden layout)
    gemm_i8<EPI_GELU><<<dim3(HIDD / 128, NTOK / 256), 512, 0, stream>>>(
        h2, wfc1_s, NTOK, HIDD, CDIM, a_fc1, b_fc1, h2scale, m1, nullptr);

    // fc2 + final residual: out(f32) = x1 + ls2*(af2*acc/16 + bf2)
    gemm_resid<true><<<dim3(CDIM / 64, NTOK / 128), 256, 0, stream>>>(
        m1, wfc2_s, CDIM, HIDD, a_fc2, b_fc2, ls2_g, x1b, 1.0f / MSCALE_INV, out, nullptr);
}